// Round 19
// baseline (456.739 us; speedup 1.0000x reference)
//
#include <hip/hip_runtime.h>
#include <hip/hip_bf16.h>
#include <cstdint>
#include <cmath>

typedef __attribute__((ext_vector_type(4))) float f32x4;
typedef __attribute__((ext_vector_type(8))) short bf16x8;

#define BAR()   __builtin_amdgcn_s_barrier()
#define PRIO1() __builtin_amdgcn_s_setprio(1)
#define PRIO0() __builtin_amdgcn_s_setprio(0)
#define WAITV6() asm volatile("s_waitcnt vmcnt(6)" ::: "memory")
#define WAITV0() asm volatile("s_waitcnt vmcnt(0)" ::: "memory")
#define MM(a,b,c) __builtin_amdgcn_mfma_f32_16x16x32_bf16((a),(b),(c),0,0,0)

__device__ __forceinline__ void gl_lds16(const __hip_bfloat16* g, char* l) {
    __builtin_amdgcn_global_load_lds(
        (const __attribute__((address_space(1))) void*)g,
        (__attribute__((address_space(3))) void*)l, 16, 0, 0);
}
// NT: non-temporal C store (nt flag: no-allocate/evict-first) — avoids the
// 96MB C stream evicting the A/B read set from L2/L3 (R19 probe).
template<bool NT>
__device__ __forceinline__ void stc(float* C, size_t i, float v) {
    if (NT) __builtin_nontemporal_store(v, C + i);
    else    C[i] = v;
}
template<bool NT>
__device__ __forceinline__ void stc(__hip_bfloat16* C, size_t i, float v) {
    __hip_bfloat16 h = __float2bfloat16(v);
    if (NT) __builtin_nontemporal_store(*reinterpret_cast<unsigned short*>(&h),
                                        reinterpret_cast<unsigned short*>(C + i));
    else    C[i] = h;
}
__device__ __forceinline__ float2 cmul(float2 a, float2 b) {
    return make_float2(fmaf(a.x, b.x, -(a.y * b.y)), fmaf(a.x, b.y, a.y * b.x));
}

// ===========================================================================
// gemm8p (R10-proven 4-phase schedule, unchanged main loop) + fusions:
//  - RFUSE (QKV only): interleaved-pair RoPE in the epilogue for cols < 4096.
//    Rotations COMPUTED, not fetched (R15/R16): per ni, 3 tab entries (base
//    e^{i n0 f}, increments e^{i f}, e^{i 16 f}; pos = arange), advanced by
//    complex multiply; mi-outer/ni-inner stores (write-combining, R16);
//    tab reads hoisted to the prologue (drain under prologue vmcnt(6), R17).
//  - NTC: non-temporal C stores (MODE0 = QKV/out-proj): C is not re-read
//    soon; keeping it out of L2/L3 protects the 56MB A/B read set
//    (QKV FETCH anomaly: 328MB measured vs ~56MB ideal).
//  - MODE 1 (causal S, triangular 256-blocks, nbx = ntri = 36/batch):
//    blocks with blockIdx.x >= nbx transpose V into Vt on the idle CUs.
// MODE 0: dense + bijective XCD swizzle. MODE 2: PV, kend = bm0+256,
// diagonal-shifted map. Schedule: 4 phases/K64-tile, groups = phase
// read-sets, stage {ph1:B0(t+1), ph2:A0(t+2), ph3:B1(t+2), ph4:A1(t+2)},
// vmcnt(6) once per tile at ph4 (R10 ledger).
// Structural plateau (R7-R17): ~950 TF/round, MfmaUtil 41-43% across six
// schedule variants; 1 block/CU (128KB LDS + ~190 VGPR) precludes
// cross-block stall cover; 128-tile 2-block alternative measured slower.
// ===========================================================================
#define SGA8(dd, h, i, kt) do{ const int s_ = (h)*16 + (i)*8 + w; \
    gl_lds16(Asb + (size_t)((s_>>1)<<4) * lda + ((s_&1)<<5) + (kt), \
             lds + (dd)*65536 + (s_<<10)); }while(0)
#define SGB8N(dd, g, kt) do{ const int sB_ = (g)*8 + w; \
    const int hi_ = sB_ >> 4, r_ = sB_ & 15; \
    const int wc_ = r_ >> 2, ni_ = hi_*2 + ((r_>>1)&1), kk_ = r_ & 1; \
    gl_lds16(Bsb + (size_t)(wc_*64 + ni_*16) * ldb + (kk_<<5) + (kt), \
             lds + (dd)*65536 + 32768 + (sB_<<10)); }while(0)
#define LDA8(dd, miA, kk) (*(const bf16x8*)(lds + (dd)*65536 + ((sbA + (miA)*2 + (kk)) << 10) + rswz))
#define LDB8N(dd, ni, kk) (*(const bf16x8*)(lds + (dd)*65536 + 32768 + \
    ((((((ni)>>1)<<4) + ((w&3)<<2) + (((ni)&1)<<1) + (kk))) << 10) + rswz))

template<typename CT, int MODE, bool RFUSE, bool NTC>
__global__ __launch_bounds__(512, 2)
void gemm8p(const __hip_bfloat16* __restrict__ A, const __hip_bfloat16* __restrict__ B,
            CT* __restrict__ C, int K, int lda, int ldb, int ldc, int nbx,
            float alpha, size_t sA, size_t sB, size_t sC,
            const float2* __restrict__ tab,
            const __hip_bfloat16* __restrict__ Vsrc,
            __hip_bfloat16* __restrict__ Vt, int ldv)
{
    __shared__ __align__(1024) char lds[131072];
    const int tid = threadIdx.x;

    int bm0, bn0;
    if (MODE == 1) {
        if ((int)blockIdx.x >= nbx) {
            // ---- V-transpose worker (fills idle CUs of the S grid) ----
            const int tb  = blockIdx.x - nbx;
            const int ntb = gridDim.x - nbx;
            const __hip_bfloat16* Vg = Vsrc + (size_t)blockIdx.y * 2048 * ldv;
            __hip_bfloat16* Vtg = Vt + (size_t)blockIdx.y * 2048 * 2048;
            __hip_bfloat16 (*tile)[66] = (__hip_bfloat16(*)[66])lds;
            const int tx = tid & 63, ty = tid >> 6;     // 64 x 8
            for (int ti = tb; ti < 1024; ti += ntb) {
                const int k0 = (ti & 31) << 6, d0 = (ti >> 5) << 6;
                __syncthreads();
#pragma unroll
                for (int jj = 0; jj < 8; ++jj)
                    tile[ty + 8 * jj][tx] = Vg[(size_t)(k0 + ty + 8 * jj) * ldv + d0 + tx];
                __syncthreads();
#pragma unroll
                for (int jj = 0; jj < 8; ++jj)
                    Vtg[(size_t)(d0 + ty + 8 * jj) * 2048 + k0 + tx] = tile[tx][ty + 8 * jj];
            }
            return;
        }
        const int wgi = blockIdx.x;
        int by = (int)((sqrtf(8.f * wgi + 1.f) - 1.f) * 0.5f);
        if (by * (by + 1) / 2 > wgi) --by;
        if ((by + 1) * (by + 2) / 2 <= wgi) ++by;
        const int bx = wgi - by * (by + 1) / 2;
        bm0 = by * 256; bn0 = bx * 256;
    } else if (MODE == 2) {
        const int g = blockIdx.x;
        const int nby = gridDim.x / nbx;
        const int bx = g % nbx;
        const int by = (g / nbx + bx) % nby;
        bm0 = by * 256; bn0 = bx * 256;
    } else {
        const int nwg = gridDim.x;
        const int q8 = nwg >> 3, r8 = nwg & 7;
        const int xcd = blockIdx.x & 7, blk = blockIdx.x >> 3;
        const int wg = (xcd < r8 ? xcd * (q8 + 1) : r8 * (q8 + 1) + (xcd - r8) * q8) + blk;
        bm0 = (wg / nbx) * 256; bn0 = (wg % nbx) * 256;
    }

    A += sA * blockIdx.y; B += sB * blockIdx.y; C += sC * blockIdx.y;

    const int lane = tid & 63;
    const int w    = tid >> 6;

    const int rb   = (lane & 15) * 64 + (lane >> 4) * 16;
    const int rswz = rb ^ (((rb >> 9) & 1) << 5);
    const int sbA  = (w >> 2) * 16;

    const int l16 = lane * 16;
    const int uqs = l16 ^ (((l16 >> 9) & 1) << 5);
    const int rIn = uqs >> 6;
    const int cIn = (uqs & 63) >> 1;
    const __hip_bfloat16* Asb = A + (size_t)(bm0 + rIn) * lda + cIn;
    const __hip_bfloat16* Bsb = B + (size_t)(bn0 + rIn) * ldb + cIn;

    f32x4 acc[8][4] = {};
    bf16x8 afA[4][2], bfB[2][2];

    const int klim = bm0 + 256;
    const int kend = (MODE == 2) ? (K < klim ? K : klim) : K;
    const int nt   = kend >> 6;

    // epilogue constants (needed for the hoisted tab reads)
    const int cr = (lane >> 4) * 4, cc = lane & 15;
    const int wrow = bm0 + (w >> 2) * 128, wcol = bn0 + (w & 3) * 64;

    // hoisted RFUSE table reads — drain under the prologue WAITV6
    float2 r1[4], r16[4], cmi[4];
    const bool dorope = RFUSE && bn0 < 4096;
    if (dorope) {
        const int n0 = (wrow + cr) & 2047;
#pragma unroll
        for (int ni = 0; ni < 4; ++ni) {
            const int col = wcol + ni * 16 + cc;
            const int j0  = (col & 127) >> 1;
            r1[ni]  = tab[(1  << 6) | j0];
            r16[ni] = tab[(16 << 6) | j0];
            cmi[ni] = tab[(n0 << 6) | j0];
        }
    }

    // prologue: tile0 {A0,B0,B1,A1} + tile1 {A0,B1,A1}
    SGA8(0, 0, 0, 0); SGA8(0, 1, 0, 0);            // A0(0)
    SGB8N(0, 0, 0);   SGB8N(0, 1, 0);              // B0(0)
    SGB8N(0, 2, 0);   SGB8N(0, 3, 0);              // B1(0)
    SGA8(0, 0, 1, 0); SGA8(0, 1, 1, 0);            // A1(0)
    if (nt > 1) {
        SGA8(1, 0, 0, 64); SGA8(1, 1, 0, 64);      // A0(1)
        SGB8N(1, 2, 64);   SGB8N(1, 3, 64);        // B1(1)
        SGA8(1, 0, 1, 64); SGA8(1, 1, 1, 64);      // A1(1)
        WAITV6();
    } else WAITV0();
    BAR();

    for (int t = 0; t < nt; ++t) {
        const int d   = t & 1, e = d ^ 1;
        const bool p1 = (t + 1) < nt;
        const bool p2 = (t + 2) < nt;
        const int kt1 = (t + 1) << 6;
        const int kt2 = (t + 2) << 6;

        // ---- ph1: (mL,nL) — read A0+B0 frags; stage B0(t+1)->e
#pragma unroll
        for (int mi = 0; mi < 4; ++mi) { afA[mi][0] = LDA8(d, mi, 0); afA[mi][1] = LDA8(d, mi, 1); }
#pragma unroll
        for (int ni = 0; ni < 2; ++ni) { bfB[ni][0] = LDB8N(d, ni, 0); bfB[ni][1] = LDB8N(d, ni, 1); }
        if (p1) { SGB8N(e, 0, kt1); SGB8N(e, 1, kt1); }
        BAR();
        PRIO1();
#pragma unroll
        for (int mi = 0; mi < 4; ++mi)
#pragma unroll
            for (int ni = 0; ni < 2; ++ni) {
                f32x4 c = acc[mi][ni];
                c = MM(afA[mi][0], bfB[ni][0], c);
                c = MM(afA[mi][1], bfB[ni][1], c);
                acc[mi][ni] = c;
            }
        PRIO0();
        BAR();

        // ---- ph2: (mL,nH) — read B1 frags; stage A0(t+2)->d
#pragma unroll
        for (int ni = 0; ni < 2; ++ni) { bfB[ni][0] = LDB8N(d, 2 + ni, 0); bfB[ni][1] = LDB8N(d, 2 + ni, 1); }
        if (p2) { SGA8(d, 0, 0, kt2); SGA8(d, 1, 0, kt2); }
        BAR();
        PRIO1();
#pragma unroll
        for (int mi = 0; mi < 4; ++mi)
#pragma unroll
            for (int ni = 0; ni < 2; ++ni) {
                f32x4 c = acc[mi][2 + ni];
                c = MM(afA[mi][0], bfB[ni][0], c);
                c = MM(afA[mi][1], bfB[ni][1], c);
                acc[mi][2 + ni] = c;
            }
        PRIO0();
        BAR();

        // ---- ph3: (mH,nH) — read A1 frags; stage B1(t+2)->d
#pragma unroll
        for (int mi = 0; mi < 4; ++mi) { afA[mi][0] = LDA8(d, 4 + mi, 0); afA[mi][1] = LDA8(d, 4 + mi, 1); }
        if (p2) { SGB8N(d, 2, kt2); SGB8N(d, 3, kt2); }
        BAR();
        PRIO1();
#pragma unroll
        for (int mi = 0; mi < 4; ++mi)
#pragma unroll
            for (int ni = 0; ni < 2; ++ni) {
                f32x4 c = acc[4 + mi][2 + ni];
                c = MM(afA[mi][0], bfB[ni][0], c);
                c = MM(afA[mi][1], bfB[ni][1], c);
                acc[4 + mi][2 + ni] = c;
            }
        PRIO0();
        BAR();

        // ---- ph4: (mH,nL) — re-read B0 frags; stage A1(t+2)->d; vmcnt(6)
#pragma unroll
        for (int ni = 0; ni < 2; ++ni) { bfB[ni][0] = LDB8N(d, ni, 0); bfB[ni][1] = LDB8N(d, ni, 1); }
        if (p2) { SGA8(d, 0, 1, kt2); SGA8(d, 1, 1, kt2); WAITV6(); }
        else WAITV0();
        BAR();
        PRIO1();
#pragma unroll
        for (int mi = 0; mi < 4; ++mi)
#pragma unroll
            for (int ni = 0; ni < 2; ++ni) {
                f32x4 c = acc[4 + mi][ni];
                c = MM(afA[mi][0], bfB[ni][0], c);
                c = MM(afA[mi][1], bfB[ni][1], c);
                acc[4 + mi][ni] = c;
            }
        PRIO0();
        BAR();
    }

    // epilogue: C/D layout col=lane&15, row=(lane>>4)*4+j (m89/m91)
    if (dorope) {
#pragma unroll
        for (int mi = 0; mi < 8; ++mi)
#pragma unroll
            for (int ni = 0; ni < 4; ++ni) {
                const int row = wrow + mi * 16 + cr;
                const int col = wcol + ni * 16 + cc;
                float2 cs = cmi[ni];
#pragma unroll
                for (int j = 0; j < 4; ++j) {
                    float xv = acc[mi][ni][j] * alpha;
                    float xp = __shfl_xor(xv, 1);
                    float y = (lane & 1) ? fmaf(cs.y, xp, cs.x * xv)
                                         : fmaf(cs.x, xv, -(cs.y * xp));
                    stc<NTC>(C, (size_t)(row + j) * ldc + col, y);
                    cs = cmul(cs, r1[ni]);
                }
                cmi[ni] = cmul(cmi[ni], r16[ni]);
            }
    } else {
#pragma unroll
        for (int mi = 0; mi < 8; ++mi)
#pragma unroll
            for (int ni = 0; ni < 4; ++ni) {
                const int row = wrow + mi * 16 + cr;
                const int col = wcol + ni * 16 + cc;
#pragma unroll
                for (int j = 0; j < 4; ++j)
                    stc<NTC>(C, (size_t)(row + j) * ldc + col, acc[mi][ni][j] * alpha);
            }
    }
}

// ---------------------------------------------------------------------------
// conv5r: all 5 fp32->bf16 converts (x -> xb, wq|wk|wv -> wqkv, wo -> wob)
// PLUS the RoPE table, one dispatch. Blocks [0, 32768): converts (8M float4).
// Blocks [32768, 33280): tab[n*64+j] = (cos, sin)(pos[n] * 10000^{-j/64}).
// ---------------------------------------------------------------------------
__global__ void conv5r(const float* __restrict__ x,  const float* __restrict__ w0,
                       const float* __restrict__ w1, const float* __restrict__ w2,
                       const float* __restrict__ w3, const int* __restrict__ pos,
                       __hip_bfloat16* __restrict__ xb,
                       __hip_bfloat16* __restrict__ wqkv,
                       __hip_bfloat16* __restrict__ wob,
                       float2* __restrict__ tab)
{
    if (blockIdx.x >= 32768) {
        int idx = (blockIdx.x - 32768) * 256 + threadIdx.x;   // < 131072
        int n = idx >> 6, j = idx & 63;
        float p = (float)pos[n];
        float ang = p * powf(10000.f, -(float)j * (1.0f / 64.0f));
        tab[idx] = make_float2(cosf(ang), sinf(ang));
        return;
    }
    int i = blockIdx.x * 256 + threadIdx.x;        // over 8M float4
    const float* src; __hip_bfloat16* dst; int off;
    if (i < 4194304) { src = x; dst = xb; off = i; }
    else {
        int k = i - 4194304;
        int ws = k >> 20;
        off = k & 1048575;
        switch (ws) {
            case 0: src = w0; dst = wqkv;                     break;
            case 1: src = w1; dst = wqkv + (size_t)4194304;   break;
            case 2: src = w2; dst = wqkv + (size_t)8388608;   break;
            default: src = w3; dst = wob;                     break;
        }
    }
    float4 v = ((const float4*)src)[off];
    union { ushort4 u; __hip_bfloat16 h[4]; } o;
    o.h[0] = __float2bfloat16(v.x);
    o.h[1] = __float2bfloat16(v.y);
    o.h[2] = __float2bfloat16(v.z);
    o.h[3] = __float2bfloat16(v.w);
    ((ushort4*)dst)[off] = o.u;
}

// ---------------------------------------------------------------------------
// softmax4: one WAVE per row (4 independent waves/block, zero barriers),
// row register-cached via fully-unrolled 16-chunk loops. In-place fp32 ->
// bf16; whole row in registers before the first store. Write extent =
// 256-block boundary (PV's kend guarantees cols beyond are never read).
// ---------------------------------------------------------------------------
__global__ __launch_bounds__(256)
void softmax4(float* __restrict__ S, int N)
{
    const int tid  = threadIdx.x;
    const int lane = tid & 63;
    const int q    = blockIdx.x * 4 + (tid >> 6);
    float* srow = S + ((size_t)blockIdx.y * N + q) * N;
    const float2* s2 = (const float2*)srow;
    const int nc = (q >> 7) + 1;              // live 128-col chunks
    const int wc = ((q >> 8) + 1) << 1;       // write chunks (256-aligned)

    float2 vals[16];
    float m = -1e30f;
#pragma unroll
    for (int i = 0; i < 16; ++i) {
        float2 xv = make_float2(-1e30f, -1e30f);
        const int j = i * 128 + lane * 2;
        if (i < nc && j <= q) {
            xv = s2[i * 64 + lane];
            if (j + 1 > q) xv.y = -1e30f;
        }
        vals[i] = xv;
        m = fmaxf(m, fmaxf(xv.x, xv.y));
    }
#pragma unroll
    for (int o = 32; o > 0; o >>= 1) m = fmaxf(m, __shfl_xor(m, o));

    float sum = 0.f;
#pragma unroll
    for (int i = 0; i < 16; ++i) {
        float ex = __expf(vals[i].x - m);
        float ey = __expf(vals[i].y - m);
        vals[i] = make_float2(ex, ey);
        sum += ex + ey;
    }
#pragma unroll
    for (int o = 32; o > 0; o >>= 1) sum += __shfl_xor(sum, o);
    const float inv = 1.f / sum;

    __hip_bfloat162* p2 = (__hip_bfloat162*)srow;
#pragma unroll
    for (int i = 0; i < 16; ++i) {
        if (i < wc) {
            __hip_bfloat162 h;
            h.x = __float2bfloat16(vals[i].x * inv);
            h.y = __float2bfloat16(vals[i].y * inv);
            p2[i * 64 + lane] = h;
        }
    }
}

// ---------------------------------------------------------------------------
extern "C" void kernel_launch(void* const* d_in, const int* in_sizes, int n_in,
                              void* d_out, int out_size, void* d_ws, size_t ws_size,
                              hipStream_t stream)
{
    const float* x  = (const float*)d_in[0];
    const int* pos  = (const int*)d_in[1];
    const float* wq = (const float*)d_in[2];
    const float* wk = (const float*)d_in[3];
    const float* wv = (const float*)d_in[4];
    const float* wo = (const float*)d_in[5];
    float* out = (float*)d_out;

    const int B = 4, N = 2048, D = 2048;
    const int M = B * N;                      // 8192
    const int D3 = 3 * D;                     // 6144
    const size_t MB = 1ull << 20;
    if (ws_size < 192 * MB) return;

    char* w = (char*)d_ws;
    __hip_bfloat16* QKV  = (__hip_bfloat16*)(w + 0 * MB);    // 96 MB, ld 6144
    __hip_bfloat16* wqkv = (__hip_bfloat16*)(w + 96 * MB);   // 24 MB
    __hip_bfloat16* wob  = (__hip_bfloat16*)(w + 120 * MB);  //  8 MB
    __hip_bfloat16* xb   = (__hip_bfloat16*)(w + 128 * MB);  // 32 MB, dead after QKV GEMM
    __hip_bfloat16* Vt   = xb;                               // alias
    __hip_bfloat16* AO   = (__hip_bfloat16*)(w + 160 * MB);  // 32 MB
    float2*         tab  = (float2*)(w + 190 * MB);          //  1 MB

    __hip_bfloat16* Qb = QKV;
    __hip_bfloat16* Kb = QKV + D;
    __hip_bfloat16* Vb = QKV + 2 * D;

    float* Sal = (float*)d_out;              // S scratch = d_out (64 MB)

    // 1. converts + RoPE table, one dispatch
    conv5r<<<33280, 256, 0, stream>>>(x, wq, wk, wv, wo, pos, xb, wqkv, wob, tab);

    // 2. fused QKV projection with in-epilogue RoPE on Q,K (768 wgs, NT C)
    gemm8p<__hip_bfloat16, 0, true, true><<<dim3((D3 / 256) * (M / 256)), 512, 0, stream>>>(
        xb, wqkv, QKV, D, D, D, D3, D3 / 256, 1.f, 0, 0, 0, tab, nullptr, nullptr, 0);

    // 3. attention: S (triangular, 36/batch) + V-transpose on idle blocks
    const float scale = 1.0f / sqrtf((float)D);
    const int nbxA = N / 256;                           // 8
    const int ntri = nbxA * (nbxA + 1) / 2;             // 36
    gemm8p<float, 1, false, false><<<dim3(64, B), 512, 0, stream>>>(
        Qb, Kb, Sal, D, D3, D3, N, ntri, scale,
        (size_t)N * D3, (size_t)N * D3, (size_t)N * N, nullptr, Vb, Vt, D3);
    softmax4<<<dim3(N / 4, B), 256, 0, stream>>>(Sal, N);
    gemm8p<__hip_bfloat16, 2, false, false><<<dim3(nbxA * nbxA, B), 512, 0, stream>>>(
        (const __hip_bfloat16*)Sal, Vt, AO, N, 2 * N, N, D, nbxA, 1.f,
        (size_t)2 * N * N, (size_t)N * N, (size_t)N * D, nullptr, nullptr, nullptr, 0);

    // 4. output projection (NT C: final output, never re-read)
    gemm8p<float, 0, false, true><<<dim3((D / 256) * (M / 256)), 512, 0, stream>>>(
        AO, wob, out, D, D, D, D, D / 256, 1.f, 0, 0, 0, nullptr, nullptr, nullptr, 0);
}

// Round 20
// 420.642 us; speedup vs baseline: 1.0858x; 1.0858x over previous
//
#include <hip/hip_runtime.h>
#include <hip/hip_bf16.h>
#include <cstdint>
#include <cmath>

typedef __attribute__((ext_vector_type(4))) float f32x4;
typedef __attribute__((ext_vector_type(8))) short bf16x8;

#define BAR()   __builtin_amdgcn_s_barrier()
#define PRIO1() __builtin_amdgcn_s_setprio(1)
#define PRIO0() __builtin_amdgcn_s_setprio(0)
#define WAITV6() asm volatile("s_waitcnt vmcnt(6)" ::: "memory")
#define WAITV0() asm volatile("s_waitcnt vmcnt(0)" ::: "memory")
#define MM(a,b,c) __builtin_amdgcn_mfma_f32_16x16x32_bf16((a),(b),(c),0,0,0)

__device__ __forceinline__ void gl_lds16(const __hip_bfloat16* g, char* l) {
    __builtin_amdgcn_global_load_lds(
        (const __attribute__((address_space(1))) void*)g,
        (__attribute__((address_space(3))) void*)l, 16, 0, 0);
}
__device__ __forceinline__ void store_c(float* C, size_t i, float v) { C[i] = v; }
__device__ __forceinline__ void store_c(__hip_bfloat16* C, size_t i, float v) { C[i] = __float2bfloat16(v); }
__device__ __forceinline__ float2 cmul(float2 a, float2 b) {
    return make_float2(fmaf(a.x, b.x, -(a.y * b.y)), fmaf(a.x, b.y, a.y * b.x));
}

// ===========================================================================
// R20 = exact revert to R18 (best, 422.1us). R19's non-temporal C stores
// REGRESSED (QKV 214->240us, WRITE 98->218MB): nt on scalar 2-byte bf16
// stores defeats L2 write-combining -> partial-line RMW at HBM. Cached
// stores restored everywhere.
//
// gemm8p (R10-proven 4-phase schedule) + fusions:
//  - RFUSE (QKV only): interleaved-pair RoPE in the epilogue for cols < 4096.
//    Rotations COMPUTED, not fetched (R15/R16): per ni, 3 tab entries (base
//    e^{i n0 f}, increments e^{i f}, e^{i 16 f}; pos = arange), advanced by
//    complex multiply; mi-outer/ni-inner stores (write-combining, R16);
//    tab reads hoisted to the prologue (drain under prologue vmcnt(6), R17).
//  - MODE 1 (causal S, triangular 256-blocks, nbx = ntri = 36/batch):
//    blocks with blockIdx.x >= nbx transpose V into Vt on the idle CUs.
// MODE 0: dense + bijective XCD swizzle. MODE 2: PV, kend = bm0+256,
// diagonal-shifted map. Schedule: 4 phases/K64-tile, groups = phase
// read-sets, stage {ph1:B0(t+1), ph2:A0(t+2), ph3:B1(t+2), ph4:A1(t+2)},
// vmcnt(6) once per tile at ph4 (R10 ledger).
// Structural plateau (R7-R17): ~950 TF/round, MfmaUtil 41-43% across six
// schedule variants; 1 block/CU (128KB LDS + ~190 VGPR) precludes
// cross-block stall cover; 128-tile 2-block alternative measured slower.
// FETCH anomaly (~320MB vs 56MB ideal) = cross-XCD L2 duplication of the
// shared A/B panels (8 x 56MB bound) — topology, not store policy (R19).
// ===========================================================================
#define SGA8(dd, h, i, kt) do{ const int s_ = (h)*16 + (i)*8 + w; \
    gl_lds16(Asb + (size_t)((s_>>1)<<4) * lda + ((s_&1)<<5) + (kt), \
             lds + (dd)*65536 + (s_<<10)); }while(0)
#define SGB8N(dd, g, kt) do{ const int sB_ = (g)*8 + w; \
    const int hi_ = sB_ >> 4, r_ = sB_ & 15; \
    const int wc_ = r_ >> 2, ni_ = hi_*2 + ((r_>>1)&1), kk_ = r_ & 1; \
    gl_lds16(Bsb + (size_t)(wc_*64 + ni_*16) * ldb + (kk_<<5) + (kt), \
             lds + (dd)*65536 + 32768 + (sB_<<10)); }while(0)
#define LDA8(dd, miA, kk) (*(const bf16x8*)(lds + (dd)*65536 + ((sbA + (miA)*2 + (kk)) << 10) + rswz))
#define LDB8N(dd, ni, kk) (*(const bf16x8*)(lds + (dd)*65536 + 32768 + \
    ((((((ni)>>1)<<4) + ((w&3)<<2) + (((ni)&1)<<1) + (kk))) << 10) + rswz))

template<typename CT, int MODE, bool RFUSE>
__global__ __launch_bounds__(512, 2)
void gemm8p(const __hip_bfloat16* __restrict__ A, const __hip_bfloat16* __restrict__ B,
            CT* __restrict__ C, int K, int lda, int ldb, int ldc, int nbx,
            float alpha, size_t sA, size_t sB, size_t sC,
            const float2* __restrict__ tab,
            const __hip_bfloat16* __restrict__ Vsrc,
            __hip_bfloat16* __restrict__ Vt, int ldv)
{
    __shared__ __align__(1024) char lds[131072];
    const int tid = threadIdx.x;

    int bm0, bn0;
    if (MODE == 1) {
        if ((int)blockIdx.x >= nbx) {
            // ---- V-transpose worker (fills idle CUs of the S grid) ----
            const int tb  = blockIdx.x - nbx;
            const int ntb = gridDim.x - nbx;
            const __hip_bfloat16* Vg = Vsrc + (size_t)blockIdx.y * 2048 * ldv;
            __hip_bfloat16* Vtg = Vt + (size_t)blockIdx.y * 2048 * 2048;
            __hip_bfloat16 (*tile)[66] = (__hip_bfloat16(*)[66])lds;
            const int tx = tid & 63, ty = tid >> 6;     // 64 x 8
            for (int ti = tb; ti < 1024; ti += ntb) {
                const int k0 = (ti & 31) << 6, d0 = (ti >> 5) << 6;
                __syncthreads();
#pragma unroll
                for (int jj = 0; jj < 8; ++jj)
                    tile[ty + 8 * jj][tx] = Vg[(size_t)(k0 + ty + 8 * jj) * ldv + d0 + tx];
                __syncthreads();
#pragma unroll
                for (int jj = 0; jj < 8; ++jj)
                    Vtg[(size_t)(d0 + ty + 8 * jj) * 2048 + k0 + tx] = tile[tx][ty + 8 * jj];
            }
            return;
        }
        const int wgi = blockIdx.x;
        int by = (int)((sqrtf(8.f * wgi + 1.f) - 1.f) * 0.5f);
        if (by * (by + 1) / 2 > wgi) --by;
        if ((by + 1) * (by + 2) / 2 <= wgi) ++by;
        const int bx = wgi - by * (by + 1) / 2;
        bm0 = by * 256; bn0 = bx * 256;
    } else if (MODE == 2) {
        const int g = blockIdx.x;
        const int nby = gridDim.x / nbx;
        const int bx = g % nbx;
        const int by = (g / nbx + bx) % nby;
        bm0 = by * 256; bn0 = bx * 256;
    } else {
        const int nwg = gridDim.x;
        const int q8 = nwg >> 3, r8 = nwg & 7;
        const int xcd = blockIdx.x & 7, blk = blockIdx.x >> 3;
        const int wg = (xcd < r8 ? xcd * (q8 + 1) : r8 * (q8 + 1) + (xcd - r8) * q8) + blk;
        bm0 = (wg / nbx) * 256; bn0 = (wg % nbx) * 256;
    }

    A += sA * blockIdx.y; B += sB * blockIdx.y; C += sC * blockIdx.y;

    const int lane = tid & 63;
    const int w    = tid >> 6;

    const int rb   = (lane & 15) * 64 + (lane >> 4) * 16;
    const int rswz = rb ^ (((rb >> 9) & 1) << 5);
    const int sbA  = (w >> 2) * 16;

    const int l16 = lane * 16;
    const int uqs = l16 ^ (((l16 >> 9) & 1) << 5);
    const int rIn = uqs >> 6;
    const int cIn = (uqs & 63) >> 1;
    const __hip_bfloat16* Asb = A + (size_t)(bm0 + rIn) * lda + cIn;
    const __hip_bfloat16* Bsb = B + (size_t)(bn0 + rIn) * ldb + cIn;

    f32x4 acc[8][4] = {};
    bf16x8 afA[4][2], bfB[2][2];

    const int klim = bm0 + 256;
    const int kend = (MODE == 2) ? (K < klim ? K : klim) : K;
    const int nt   = kend >> 6;

    // epilogue constants (needed for the hoisted tab reads)
    const int cr = (lane >> 4) * 4, cc = lane & 15;
    const int wrow = bm0 + (w >> 2) * 128, wcol = bn0 + (w & 3) * 64;

    // hoisted RFUSE table reads — drain under the prologue WAITV6
    float2 r1[4], r16[4], cmi[4];
    const bool dorope = RFUSE && bn0 < 4096;
    if (dorope) {
        const int n0 = (wrow + cr) & 2047;
#pragma unroll
        for (int ni = 0; ni < 4; ++ni) {
            const int col = wcol + ni * 16 + cc;
            const int j0  = (col & 127) >> 1;
            r1[ni]  = tab[(1  << 6) | j0];
            r16[ni] = tab[(16 << 6) | j0];
            cmi[ni] = tab[(n0 << 6) | j0];
        }
    }

    // prologue: tile0 {A0,B0,B1,A1} + tile1 {A0,B1,A1}
    SGA8(0, 0, 0, 0); SGA8(0, 1, 0, 0);            // A0(0)
    SGB8N(0, 0, 0);   SGB8N(0, 1, 0);              // B0(0)
    SGB8N(0, 2, 0);   SGB8N(0, 3, 0);              // B1(0)
    SGA8(0, 0, 1, 0); SGA8(0, 1, 1, 0);            // A1(0)
    if (nt > 1) {
        SGA8(1, 0, 0, 64); SGA8(1, 1, 0, 64);      // A0(1)
        SGB8N(1, 2, 64);   SGB8N(1, 3, 64);        // B1(1)
        SGA8(1, 0, 1, 64); SGA8(1, 1, 1, 64);      // A1(1)
        WAITV6();
    } else WAITV0();
    BAR();

    for (int t = 0; t < nt; ++t) {
        const int d   = t & 1, e = d ^ 1;
        const bool p1 = (t + 1) < nt;
        const bool p2 = (t + 2) < nt;
        const int kt1 = (t + 1) << 6;
        const int kt2 = (t + 2) << 6;

        // ---- ph1: (mL,nL) — read A0+B0 frags; stage B0(t+1)->e
#pragma unroll
        for (int mi = 0; mi < 4; ++mi) { afA[mi][0] = LDA8(d, mi, 0); afA[mi][1] = LDA8(d, mi, 1); }
#pragma unroll
        for (int ni = 0; ni < 2; ++ni) { bfB[ni][0] = LDB8N(d, ni, 0); bfB[ni][1] = LDB8N(d, ni, 1); }
        if (p1) { SGB8N(e, 0, kt1); SGB8N(e, 1, kt1); }
        BAR();
        PRIO1();
#pragma unroll
        for (int mi = 0; mi < 4; ++mi)
#pragma unroll
            for (int ni = 0; ni < 2; ++ni) {
                f32x4 c = acc[mi][ni];
                c = MM(afA[mi][0], bfB[ni][0], c);
                c = MM(afA[mi][1], bfB[ni][1], c);
                acc[mi][ni] = c;
            }
        PRIO0();
        BAR();

        // ---- ph2: (mL,nH) — read B1 frags; stage A0(t+2)->d
#pragma unroll
        for (int ni = 0; ni < 2; ++ni) { bfB[ni][0] = LDB8N(d, 2 + ni, 0); bfB[ni][1] = LDB8N(d, 2 + ni, 1); }
        if (p2) { SGA8(d, 0, 0, kt2); SGA8(d, 1, 0, kt2); }
        BAR();
        PRIO1();
#pragma unroll
        for (int mi = 0; mi < 4; ++mi)
#pragma unroll
            for (int ni = 0; ni < 2; ++ni) {
                f32x4 c = acc[mi][2 + ni];
                c = MM(afA[mi][0], bfB[ni][0], c);
                c = MM(afA[mi][1], bfB[ni][1], c);
                acc[mi][2 + ni] = c;
            }
        PRIO0();
        BAR();

        // ---- ph3: (mH,nH) — read A1 frags; stage B1(t+2)->d
#pragma unroll
        for (int mi = 0; mi < 4; ++mi) { afA[mi][0] = LDA8(d, 4 + mi, 0); afA[mi][1] = LDA8(d, 4 + mi, 1); }
        if (p2) { SGB8N(d, 2, kt2); SGB8N(d, 3, kt2); }
        BAR();
        PRIO1();
#pragma unroll
        for (int mi = 0; mi < 4; ++mi)
#pragma unroll
            for (int ni = 0; ni < 2; ++ni) {
                f32x4 c = acc[4 + mi][2 + ni];
                c = MM(afA[mi][0], bfB[ni][0], c);
                c = MM(afA[mi][1], bfB[ni][1], c);
                acc[4 + mi][2 + ni] = c;
            }
        PRIO0();
        BAR();

        // ---- ph4: (mH,nL) — re-read B0 frags; stage A1(t+2)->d; vmcnt(6)
#pragma unroll
        for (int ni = 0; ni < 2; ++ni) { bfB[ni][0] = LDB8N(d, ni, 0); bfB[ni][1] = LDB8N(d, ni, 1); }
        if (p2) { SGA8(d, 0, 1, kt2); SGA8(d, 1, 1, kt2); WAITV6(); }
        else WAITV0();
        BAR();
        PRIO1();
#pragma unroll
        for (int mi = 0; mi < 4; ++mi)
#pragma unroll
            for (int ni = 0; ni < 2; ++ni) {
                f32x4 c = acc[4 + mi][ni];
                c = MM(afA[mi][0], bfB[ni][0], c);
                c = MM(afA[mi][1], bfB[ni][1], c);
                acc[4 + mi][ni] = c;
            }
        PRIO0();
        BAR();
    }

    // epilogue: C/D layout col=lane&15, row=(lane>>4)*4+j (m89/m91)
    if (dorope) {
#pragma unroll
        for (int mi = 0; mi < 8; ++mi)
#pragma unroll
            for (int ni = 0; ni < 4; ++ni) {
                const int row = wrow + mi * 16 + cr;
                const int col = wcol + ni * 16 + cc;
                float2 cs = cmi[ni];
#pragma unroll
                for (int j = 0; j < 4; ++j) {
                    float xv = acc[mi][ni][j] * alpha;
                    float xp = __shfl_xor(xv, 1);
                    float y = (lane & 1) ? fmaf(cs.y, xp, cs.x * xv)
                                         : fmaf(cs.x, xv, -(cs.y * xp));
                    store_c(C, (size_t)(row + j) * ldc + col, y);
                    cs = cmul(cs, r1[ni]);
                }
                cmi[ni] = cmul(cmi[ni], r16[ni]);
            }
    } else {
#pragma unroll
        for (int mi = 0; mi < 8; ++mi)
#pragma unroll
            for (int ni = 0; ni < 4; ++ni) {
                const int row = wrow + mi * 16 + cr;
                const int col = wcol + ni * 16 + cc;
#pragma unroll
                for (int j = 0; j < 4; ++j)
                    store_c(C, (size_t)(row + j) * ldc + col, acc[mi][ni][j] * alpha);
            }
    }
}

// ---------------------------------------------------------------------------
// conv5r: all 5 fp32->bf16 converts (x -> xb, wq|wk|wv -> wqkv, wo -> wob)
// PLUS the RoPE table, one dispatch. Blocks [0, 32768): converts (8M float4).
// Blocks [32768, 33280): tab[n*64+j] = (cos, sin)(pos[n] * 10000^{-j/64}).
// ---------------------------------------------------------------------------
__global__ void conv5r(const float* __restrict__ x,  const float* __restrict__ w0,
                       const float* __restrict__ w1, const float* __restrict__ w2,
                       const float* __restrict__ w3, const int* __restrict__ pos,
                       __hip_bfloat16* __restrict__ xb,
                       __hip_bfloat16* __restrict__ wqkv,
                       __hip_bfloat16* __restrict__ wob,
                       float2* __restrict__ tab)
{
    if (blockIdx.x >= 32768) {
        int idx = (blockIdx.x - 32768) * 256 + threadIdx.x;   // < 131072
        int n = idx >> 6, j = idx & 63;
        float p = (float)pos[n];
        float ang = p * powf(10000.f, -(float)j * (1.0f / 64.0f));
        tab[idx] = make_float2(cosf(ang), sinf(ang));
        return;
    }
    int i = blockIdx.x * 256 + threadIdx.x;        // over 8M float4
    const float* src; __hip_bfloat16* dst; int off;
    if (i < 4194304) { src = x; dst = xb; off = i; }
    else {
        int k = i - 4194304;
        int ws = k >> 20;
        off = k & 1048575;
        switch (ws) {
            case 0: src = w0; dst = wqkv;                     break;
            case 1: src = w1; dst = wqkv + (size_t)4194304;   break;
            case 2: src = w2; dst = wqkv + (size_t)8388608;   break;
            default: src = w3; dst = wob;                     break;
        }
    }
    float4 v = ((const float4*)src)[off];
    union { ushort4 u; __hip_bfloat16 h[4]; } o;
    o.h[0] = __float2bfloat16(v.x);
    o.h[1] = __float2bfloat16(v.y);
    o.h[2] = __float2bfloat16(v.z);
    o.h[3] = __float2bfloat16(v.w);
    ((ushort4*)dst)[off] = o.u;
}

// ---------------------------------------------------------------------------
// softmax4: one WAVE per row (4 independent waves/block, zero barriers),
// row register-cached via fully-unrolled 16-chunk loops. In-place fp32 ->
// bf16; whole row in registers before the first store. Write extent =
// 256-block boundary (PV's kend guarantees cols beyond are never read).
// ---------------------------------------------------------------------------
__global__ __launch_bounds__(256)
void softmax4(float* __restrict__ S, int N)
{
    const int tid  = threadIdx.x;
    const int lane = tid & 63;
    const int q    = blockIdx.x * 4 + (tid >> 6);
    float* srow = S + ((size_t)blockIdx.y * N + q) * N;
    const float2* s2 = (const float2*)srow;
    const int nc = (q >> 7) + 1;              // live 128-col chunks
    const int wc = ((q >> 8) + 1) << 1;       // write chunks (256-aligned)

    float2 vals[16];
    float m = -1e30f;
#pragma unroll
    for (int i = 0; i < 16; ++i) {
        float2 xv = make_float2(-1e30f, -1e30f);
        const int j = i * 128 + lane * 2;
        if (i < nc && j <= q) {
            xv = s2[i * 64 + lane];
            if (j + 1 > q) xv.y = -1e30f;
        }
        vals[i] = xv;
        m = fmaxf(m, fmaxf(xv.x, xv.y));
    }
#pragma unroll
    for (int o = 32; o > 0; o >>= 1) m = fmaxf(m, __shfl_xor(m, o));

    float sum = 0.f;
#pragma unroll
    for (int i = 0; i < 16; ++i) {
        float ex = __expf(vals[i].x - m);
        float ey = __expf(vals[i].y - m);
        vals[i] = make_float2(ex, ey);
        sum += ex + ey;
    }
#pragma unroll
    for (int o = 32; o > 0; o >>= 1) sum += __shfl_xor(sum, o);
    const float inv = 1.f / sum;

    __hip_bfloat162* p2 = (__hip_bfloat162*)srow;
#pragma unroll
    for (int i = 0; i < 16; ++i) {
        if (i < wc) {
            __hip_bfloat162 h;
            h.x = __float2bfloat16(vals[i].x * inv);
            h.y = __float2bfloat16(vals[i].y * inv);
            p2[i * 64 + lane] = h;
        }
    }
}

// ---------------------------------------------------------------------------
extern "C" void kernel_launch(void* const* d_in, const int* in_sizes, int n_in,
                              void* d_out, int out_size, void* d_ws, size_t ws_size,
                              hipStream_t stream)
{
    const float* x  = (const float*)d_in[0];
    const int* pos  = (const int*)d_in[1];
    const float* wq = (const float*)d_in[2];
    const float* wk = (const float*)d_in[3];
    const float* wv = (const float*)d_in[4];
    const float* wo = (const float*)d_in[5];
    float* out = (float*)d_out;

    const int B = 4, N = 2048, D = 2048;
    const int M = B * N;                      // 8192
    const int D3 = 3 * D;                     // 6144
    const size_t MB = 1ull << 20;
    if (ws_size < 192 * MB) return;

    char* w = (char*)d_ws;
    __hip_bfloat16* QKV  = (__hip_bfloat16*)(w + 0 * MB);    // 96 MB, ld 6144
    __hip_bfloat16* wqkv = (__hip_bfloat16*)(w + 96 * MB);   // 24 MB
    __hip_bfloat16* wob  = (__hip_bfloat16*)(w + 120 * MB);  //  8 MB
    __hip_bfloat16* xb   = (__hip_bfloat16*)(w + 128 * MB);  // 32 MB, dead after QKV GEMM
    __hip_bfloat16* Vt   = xb;                               // alias
    __hip_bfloat16* AO   = (__hip_bfloat16*)(w + 160 * MB);  // 32 MB
    float2*         tab  = (float2*)(w + 190 * MB);          //  1 MB

    __hip_bfloat16* Qb = QKV;
    __hip_bfloat16* Kb = QKV + D;
    __hip_bfloat16* Vb = QKV + 2 * D;

    float* Sal = (float*)d_out;              // S scratch = d_out (64 MB)

    // 1. converts + RoPE table, one dispatch
    conv5r<<<33280, 256, 0, stream>>>(x, wq, wk, wv, wo, pos, xb, wqkv, wob, tab);

    // 2. fused QKV projection with in-epilogue RoPE on Q,K (768 wgs)
    gemm8p<__hip_bfloat16, 0, true><<<dim3((D3 / 256) * (M / 256)), 512, 0, stream>>>(
        xb, wqkv, QKV, D, D, D, D3, D3 / 256, 1.f, 0, 0, 0, tab, nullptr, nullptr, 0);

    // 3. attention: S (triangular, 36/batch) + V-transpose on idle blocks
    const float scale = 1.0f / sqrtf((float)D);
    const int nbxA = N / 256;                           // 8
    const int ntri = nbxA * (nbxA + 1) / 2;             // 36
    gemm8p<float, 1, false><<<dim3(64, B), 512, 0, stream>>>(
        Qb, Kb, Sal, D, D3, D3, N, ntri, scale,
        (size_t)N * D3, (size_t)N * D3, (size_t)N * N, nullptr, Vb, Vt, D3);
    softmax4<<<dim3(N / 4, B), 256, 0, stream>>>(Sal, N);
    gemm8p<__hip_bfloat16, 2, false><<<dim3(nbxA * nbxA, B), 512, 0, stream>>>(
        (const __hip_bfloat16*)Sal, Vt, AO, N, 2 * N, N, D, nbxA, 1.f,
        (size_t)2 * N * N, (size_t)N * N, (size_t)N * D, nullptr, nullptr, nullptr, 0);

    // 4. output projection
    gemm8p<float, 0, false><<<dim3((D / 256) * (M / 256)), 512, 0, stream>>>(
        AO, wob, out, D, D, D, D, D / 256, 1.f, 0, 0, 0, nullptr, nullptr, nullptr, 0);
}